// Round 2
// baseline (1450.864 us; speedup 1.0000x reference)
//
#include <hip/hip_runtime.h>

typedef _Float16 half8_t __attribute__((ext_vector_type(8)));
typedef _Float16 half4_t __attribute__((ext_vector_type(4)));
typedef _Float16 half2_t __attribute__((ext_vector_type(2)));
typedef float floatx4 __attribute__((ext_vector_type(4)));

__device__ __forceinline__ float sigm_f(float v) {
  return __builtin_amdgcn_rcpf(1.f + __expf(-v));
}
__device__ __forceinline__ float tanh_f(float v) {
  return 2.f * __builtin_amdgcn_rcpf(1.f + __expf(-2.f * v)) - 1.f;
}

// ---------------------------------------------------------------------------
// Weight prep: swizzle into MFMA 16x16x32 B-fragment order, f16.
// Column permutation: col n -> gate=(n>>4)&3, hcol=(n>>6)*16+(n&15),
// orig_row oc = gate*128 + hcol.  Layer1 K rows: [0,184)=w_ih, [184,192)=0,
// [192,320)=w_hh.  Layer2: [0,256)=w_ih, [256,384)=w_hh.
// ---------------------------------------------------------------------------
__global__ void prep_kernel(
    const float* __restrict__ wih1f, const float* __restrict__ whh1f,
    const float* __restrict__ bih1f, const float* __restrict__ bhh1f,
    const float* __restrict__ wih1b, const float* __restrict__ whh1b,
    const float* __restrict__ bih1b, const float* __restrict__ bhh1b,
    const float* __restrict__ wih2f, const float* __restrict__ whh2f,
    const float* __restrict__ bih2f, const float* __restrict__ bhh2f,
    const float* __restrict__ wih2b, const float* __restrict__ whh2b,
    const float* __restrict__ bih2b, const float* __restrict__ bhh2b,
    const float* __restrict__ fc1w,
    _Float16* __restrict__ wswz1, _Float16* __restrict__ wswz2,
    _Float16* __restrict__ wfc, float* __restrict__ biasc) {
  const int N1 = 327680, N2 = 393216, NF = 32768, NB = 2048;
  int idx = blockIdx.x * 256 + threadIdx.x;
  if (idx < N1) {
    int d = idx / 163840;
    int r = idx - d * 163840;
    int j = r & 7, lane = (r >> 3) & 63, ntg = (r >> 9) & 31, kt = r >> 14;
    int k = kt * 32 + (lane >> 4) * 8 + j;
    int n = ntg * 16 + (lane & 15);
    int oc = ((n >> 4) & 3) * 128 + (n >> 6) * 16 + (n & 15);
    const float* wih = d ? wih1b : wih1f;
    const float* whh = d ? whh1b : whh1f;
    float v = (k < 184) ? wih[oc * 184 + k]
                        : ((k < 192) ? 0.f : whh[oc * 128 + (k - 192)]);
    wswz1[idx] = (_Float16)v;
  } else if (idx < N1 + N2) {
    int r0 = idx - N1;
    int d = r0 / 196608;
    int r = r0 - d * 196608;
    int j = r & 7, lane = (r >> 3) & 63, ntg = (r >> 9) & 31, kt = r >> 14;
    int k = kt * 32 + (lane >> 4) * 8 + j;
    int n = ntg * 16 + (lane & 15);
    int oc = ((n >> 4) & 3) * 128 + (n >> 6) * 16 + (n & 15);
    const float* wih = d ? wih2b : wih2f;
    const float* whh = d ? whh2b : whh2f;
    float v = (k < 256) ? wih[oc * 256 + k] : whh[oc * 128 + (k - 256)];
    wswz2[r0] = (_Float16)v;
  } else if (idx < N1 + N2 + NF) {
    int r = idx - (N1 + N2);
    int j = r & 7, lane = (r >> 3) & 63, ntg = (r >> 9) & 3, kt = r >> 11;
    int k = kt * 32 + (lane >> 4) * 8 + j;
    int n = ntg * 16 + (lane & 15);  // fc1 output index, no permutation
    wfc[r] = (_Float16)fc1w[n * 512 + k];
  } else if (idx < N1 + N2 + NF + NB) {
    int r = idx - (N1 + N2 + NF);
    int n = r & 511, d = (r >> 9) & 1, l = r >> 10;
    int oc = ((n >> 4) & 3) * 128 + (n >> 6) * 16 + (n & 15);
    const float* bi = l ? (d ? bih2b : bih2f) : (d ? bih1b : bih1f);
    const float* bh = l ? (d ? bhh2b : bhh2f) : (d ? bhh1b : bhh1f);
    biasc[r] = bi[oc] + bh[oc];
  }
}

// ---------------------------------------------------------------------------
// x fp32 (B,T,184) -> f16 padded (B,T,192), pad cols zeroed.
// ---------------------------------------------------------------------------
__global__ void xconv_kernel(const float* __restrict__ x,
                             _Float16* __restrict__ xp) {
  int idx = blockIdx.x * 256 + threadIdx.x;  // 163840 * 24 exactly
  int rt = idx / 24;
  int c = idx - rt * 24;
  half8_t hv;
  if (c < 23) {
    const float4 v0 = *(const float4*)(x + (size_t)rt * 184 + c * 8);
    const float4 v1 = *(const float4*)(x + (size_t)rt * 184 + c * 8 + 4);
    hv[0] = (_Float16)v0.x; hv[1] = (_Float16)v0.y;
    hv[2] = (_Float16)v0.z; hv[3] = (_Float16)v0.w;
    hv[4] = (_Float16)v1.x; hv[5] = (_Float16)v1.y;
    hv[6] = (_Float16)v1.z; hv[7] = (_Float16)v1.w;
  } else {
#pragma unroll
    for (int j = 0; j < 8; ++j) hv[j] = (_Float16)0.f;
  }
  *(half8_t*)(xp + (size_t)rt * 192 + c * 8) = hv;
}

// ---------------------------------------------------------------------------
// LSTM layer v2: 1024 threads = 16 waves, 128 batch rows/block (2 row-halves
// x 8 col-strips).  A-fragments for the input part are read DIRECTLY from
// global (f16, L1/L2-broadcast across the 8 col-strip waves); LDS holds only
// the 128x128 recurrent h.  Weights streamed in fragment order (L2-resident:
// per-XCD working set ~3 MB < 4 MB).  One block/CU.
// ---------------------------------------------------------------------------
template <int LAYER>
__global__ __launch_bounds__(1024) void lstm_kernel(
    const _Float16* __restrict__ xin, const _Float16* __restrict__ wswz,
    const float* __restrict__ biasc, _Float16* __restrict__ hout) {
  constexpr int XK = (LAYER == 1) ? 192 : 256;  // input cols (padded)
  constexpr int XT = XK / 32;                   // input k-tiles: 6 / 8
  constexpr int KT = XT + 4;                    // total k-tiles: 10 / 12
  constexpr int SH = 136;                       // h LDS row stride (f16)

  __shared__ __align__(16) _Float16 Hbuf[128 * SH];

  const int tid = threadIdx.x;
  const int wid = tid >> 6;
  const int lane = tid & 63;
  const int q = lane >> 4;
  const int l15 = lane & 15;
  const int rgp = wid >> 3;   // row half (0/1)
  const int cs = wid & 7;     // col strip
  const int rbase = rgp << 6;
  const int dir = blockIdx.y;
  const int row0 = blockIdx.x << 7;

  const _Float16* __restrict__ wd = wswz + (size_t)dir * (KT * 16384);
  const float* __restrict__ bd = biasc + (dir << 9);

  float bias_frag[4];
#pragma unroll
  for (int nt = 0; nt < 4; ++nt) bias_frag[nt] = bd[(cs << 6) + (nt << 4) + l15];

  // zero h state
  for (int i = tid; i < 128 * SH / 8; i += 1024) {
    half8_t z;
#pragma unroll
    for (int j = 0; j < 8; ++j) z[j] = (_Float16)0.f;
    *(half8_t*)(Hbuf + i * 8) = z;
  }
  __syncthreads();

  float c_state[4][4];
#pragma unroll
  for (int mt = 0; mt < 4; ++mt)
#pragma unroll
    for (int rg = 0; rg < 4; ++rg) c_state[mt][rg] = 0.f;

  for (int t = 0; t < 10; ++t) {
    const int t_eff = dir ? (9 - t) : t;

    // coalesced writeback of h_{t-1} (overlaps the GEMM's loads)
    if (t > 0) {
      const int t_prev = dir ? (10 - t) : (t - 1);
      for (int i = tid; i < 2048; i += 1024) {
        int r = i >> 4, cd = i & 15;
        *(uint4*)(hout + ((size_t)(row0 + r) * 10 + t_prev) * 256 + (dir << 7) + (cd << 3)) =
            *(const uint4*)(Hbuf + r * SH + (cd << 3));
      }
    }

    // gates(128x512) = [x_t | h_{t-1}] @ Wswz ; bias folded into acc init
    floatx4 acc[4][4];
#pragma unroll
    for (int mt = 0; mt < 4; ++mt)
#pragma unroll
      for (int nt = 0; nt < 4; ++nt) {
        floatx4 b4 = {bias_frag[nt], bias_frag[nt], bias_frag[nt], bias_frag[nt]};
        acc[mt][nt] = b4;
      }

    const _Float16* __restrict__ xrow[4];
#pragma unroll
    for (int mt = 0; mt < 4; ++mt)
      xrow[mt] = xin + ((size_t)(row0 + rbase + (mt << 4) + l15) * 10 + t_eff) * XK + (q << 3);

#pragma unroll
    for (int kt = 0; kt < KT; ++kt) {
      half8_t a[4];
      if (kt < XT) {
#pragma unroll
        for (int mt = 0; mt < 4; ++mt)
          a[mt] = *(const half8_t*)(xrow[mt] + (kt << 5));
      } else {
#pragma unroll
        for (int mt = 0; mt < 4; ++mt)
          a[mt] = *(const half8_t*)(Hbuf + (rbase + (mt << 4) + l15) * SH +
                                    ((kt - XT) << 5) + (q << 3));
      }
#pragma unroll
      for (int nt = 0; nt < 4; ++nt) {
        const half8_t b =
            *(const half8_t*)(wd + ((((size_t)kt << 5) + (cs << 2) + nt) * 64 + lane) * 8);
#pragma unroll
        for (int mt = 0; mt < 4; ++mt)
          acc[mt][nt] = __builtin_amdgcn_mfma_f32_16x16x32_f16(a[mt], b, acc[mt][nt], 0, 0, 0);
      }
    }
    __syncthreads();  // all Hbuf reads done before overwrite

    // LSTM cell: nt == gate, wave-local
#pragma unroll
    for (int mt = 0; mt < 4; ++mt) {
#pragma unroll
      for (int rg = 0; rg < 4; ++rg) {
        float ig = sigm_f(acc[mt][0][rg]);
        float fg = sigm_f(acc[mt][1][rg]);
        float gg = tanh_f(acc[mt][2][rg]);
        float og = sigm_f(acc[mt][3][rg]);
        float c = fg * c_state[mt][rg] + ig * gg;
        c_state[mt][rg] = c;
        float h = og * tanh_f(c);
        Hbuf[(rbase + (mt << 4) + (q << 2) + rg) * SH + (cs << 4) + l15] = (_Float16)h;
      }
    }
    __syncthreads();  // h_t visible to all waves
  }

  {
    const int t_last = dir ? 0 : 9;
    for (int i = tid; i < 2048; i += 1024) {
      int r = i >> 4, cd = i & 15;
      *(uint4*)(hout + ((size_t)(row0 + r) * 10 + t_last) * 256 + (dir << 7) + (cd << 3)) =
          *(const uint4*)(Hbuf + r * SH + (cd << 3));
    }
  }
}

// ---------------------------------------------------------------------------
// Maxpool (groups of 5 over T) + FC 512->64 relu -> 64->1.
// ---------------------------------------------------------------------------
__global__ __launch_bounds__(256) void fc_kernel(
    const _Float16* __restrict__ h2, const _Float16* __restrict__ wfc,
    const float* __restrict__ fc1b, const float* __restrict__ fc2w,
    const float* __restrict__ fc2b, float* __restrict__ out) {
  __shared__ __align__(16) _Float16 pooled[64 * 520];
  const int tid = threadIdx.x;
  const int s0 = blockIdx.x << 6;

  for (int idx = tid; idx < 64 * 128; idx += 256) {
    int s = idx >> 7;
    int part = idx & 127;
    const _Float16* base = h2 + (size_t)(s0 + s) * 10 * 256 + (part << 1);
    float m00 = -3.4e38f, m01 = -3.4e38f, m10 = -3.4e38f, m11 = -3.4e38f;
#pragma unroll
    for (int t = 0; t < 10; ++t) {
      half2_t hv = *(const half2_t*)(base + t * 256);
      float f0 = (float)hv[0], f1 = (float)hv[1];
      if (t < 5) { m00 = fmaxf(m00, f0); m10 = fmaxf(m10, f1); }
      else       { m01 = fmaxf(m01, f0); m11 = fmaxf(m11, f1); }
    }
    half4_t pv;
    pv[0] = (_Float16)m00; pv[1] = (_Float16)m01;
    pv[2] = (_Float16)m10; pv[3] = (_Float16)m11;
    *(half4_t*)(pooled + s * 520 + (part << 2)) = pv;
  }
  __syncthreads();

  const int wid = tid >> 6, lane = tid & 63, q = lane >> 4, l15 = lane & 15;
  const int m0 = wid << 4;

  const floatx4 fzero = {0.f, 0.f, 0.f, 0.f};
  floatx4 acc[4];
#pragma unroll
  for (int nt = 0; nt < 4; ++nt) acc[nt] = fzero;

#pragma unroll
  for (int kt = 0; kt < 16; ++kt) {
    half8_t a = *(const half8_t*)(pooled + (m0 + l15) * 520 + (kt << 5) + (q << 3));
#pragma unroll
    for (int nt = 0; nt < 4; ++nt) {
      half8_t b = *(const half8_t*)(wfc + ((((size_t)kt << 2) + nt) * 64 + lane) * 8);
      acc[nt] = __builtin_amdgcn_mfma_f32_16x16x32_f16(a, b, acc[nt], 0, 0, 0);
    }
  }

  float b1[4], w2[4];
#pragma unroll
  for (int nt = 0; nt < 4; ++nt) {
    b1[nt] = fc1b[(nt << 4) + l15];
    w2[nt] = fc2w[(nt << 4) + l15];
  }
  const float c2b = fc2b[0];

#pragma unroll
  for (int rg = 0; rg < 4; ++rg) {
    float v = 0.f;
#pragma unroll
    for (int nt = 0; nt < 4; ++nt)
      v += fmaxf(acc[nt][rg] + b1[nt], 0.f) * w2[nt];
    v += __shfl_xor(v, 1, 64);
    v += __shfl_xor(v, 2, 64);
    v += __shfl_xor(v, 4, 64);
    v += __shfl_xor(v, 8, 64);
    if (l15 == 0) out[s0 + m0 + (q << 2) + rg] = v + c2b;
  }
}

// ---------------------------------------------------------------------------
extern "C" void kernel_launch(void* const* d_in, const int* in_sizes, int n_in,
                              void* d_out, int out_size, void* d_ws, size_t ws_size,
                              hipStream_t stream) {
  const float* x     = (const float*)d_in[0];
  const float* wih1f = (const float*)d_in[1];
  const float* whh1f = (const float*)d_in[2];
  const float* bih1f = (const float*)d_in[3];
  const float* bhh1f = (const float*)d_in[4];
  const float* wih1b = (const float*)d_in[5];
  const float* whh1b = (const float*)d_in[6];
  const float* bih1b = (const float*)d_in[7];
  const float* bhh1b = (const float*)d_in[8];
  const float* wih2f = (const float*)d_in[9];
  const float* whh2f = (const float*)d_in[10];
  const float* bih2f = (const float*)d_in[11];
  const float* bhh2f = (const float*)d_in[12];
  const float* wih2b = (const float*)d_in[13];
  const float* whh2b = (const float*)d_in[14];
  const float* bih2b = (const float*)d_in[15];
  const float* bhh2b = (const float*)d_in[16];
  const float* fc1w  = (const float*)d_in[17];
  const float* fc1b  = (const float*)d_in[18];
  const float* fc2w  = (const float*)d_in[19];
  const float* fc2b  = (const float*)d_in[20];
  float* out = (float*)d_out;

  // workspace layout (169,287,680 B total, same as r1):
  //   region A (83,886,080 B): xf16p (62.9 MB) during xconv+lstm1,
  //                            then h2out (83.9 MB) during lstm2+fc
  //   region B (83,886,080 B): h1out
  //   + wswz1 / wswz2 / wfc / biasc
  if (ws_size < (size_t)169287680) return;
  _Float16* regionA = (_Float16*)d_ws;
  _Float16* xf16p = regionA;
  _Float16* h2out = regionA;
  _Float16* h1out = regionA + (size_t)41943040;
  _Float16* wswz1 = h1out + (size_t)41943040;
  _Float16* wswz2 = wswz1 + 327680;
  _Float16* wfc   = wswz2 + 393216;
  float* biasc    = (float*)(wfc + 32768);

  prep_kernel<<<2952, 256, 0, stream>>>(
      wih1f, whh1f, bih1f, bhh1f, wih1b, whh1b, bih1b, bhh1b,
      wih2f, whh2f, bih2f, bhh2f, wih2b, whh2b, bih2b, bhh2b, fc1w,
      wswz1, wswz2, wfc, biasc);
  xconv_kernel<<<15360, 256, 0, stream>>>(x, xf16p);
  lstm_kernel<1><<<dim3(128, 2), 1024, 0, stream>>>(xf16p, wswz1, biasc, h1out);
  lstm_kernel<2><<<dim3(128, 2), 1024, 0, stream>>>(h1out, wswz2, biasc + 1024, h2out);
  fc_kernel<<<256, 256, 0, stream>>>(h2out, wfc, fc1b, fc2w, fc2b, out);
}

// Round 3
// 791.639 us; speedup vs baseline: 1.8327x; 1.8327x over previous
//
#include <hip/hip_runtime.h>

typedef _Float16 half8_t __attribute__((ext_vector_type(8)));
typedef _Float16 half4_t __attribute__((ext_vector_type(4)));
typedef _Float16 half2_t __attribute__((ext_vector_type(2)));
typedef float floatx4 __attribute__((ext_vector_type(4)));

__device__ __forceinline__ float sigm_f(float v) {
  return __builtin_amdgcn_rcpf(1.f + __expf(-v));
}
__device__ __forceinline__ float tanh_f(float v) {
  return 2.f * __builtin_amdgcn_rcpf(1.f + __expf(-2.f * v)) - 1.f;
}

__device__ __forceinline__ void gl_lds16(const _Float16* g, _Float16* l) {
  __builtin_amdgcn_global_load_lds(
      (const __attribute__((address_space(1))) void*)g,
      (__attribute__((address_space(3))) void*)l, 16, 0, 0);
}

// ---------------------------------------------------------------------------
// Weight prep (unchanged layout): MFMA B-frag order, f16.
// col n -> gate=(n>>4)&3, hcol=(n>>6)*16+(n&15); oc = gate*128+hcol.
// L1 K rows: [0,184)=w_ih, [184,192)=0, [192,320)=w_hh.  L2: [0,256)=w_ih,
// [256,384)=w_hh.  wswz[dir][kt][ntg=cs*4+nt][lane][8].
// ---------------------------------------------------------------------------
__global__ void prep_kernel(
    const float* __restrict__ wih1f, const float* __restrict__ whh1f,
    const float* __restrict__ bih1f, const float* __restrict__ bhh1f,
    const float* __restrict__ wih1b, const float* __restrict__ whh1b,
    const float* __restrict__ bih1b, const float* __restrict__ bhh1b,
    const float* __restrict__ wih2f, const float* __restrict__ whh2f,
    const float* __restrict__ bih2f, const float* __restrict__ bhh2f,
    const float* __restrict__ wih2b, const float* __restrict__ whh2b,
    const float* __restrict__ bih2b, const float* __restrict__ bhh2b,
    const float* __restrict__ fc1w,
    _Float16* __restrict__ wswz1, _Float16* __restrict__ wswz2,
    _Float16* __restrict__ wfc, float* __restrict__ biasc) {
  const int N1 = 327680, N2 = 393216, NF = 32768, NB = 2048;
  int idx = blockIdx.x * 256 + threadIdx.x;
  if (idx < N1) {
    int d = idx / 163840;
    int r = idx - d * 163840;
    int j = r & 7, lane = (r >> 3) & 63, ntg = (r >> 9) & 31, kt = r >> 14;
    int k = kt * 32 + (lane >> 4) * 8 + j;
    int n = ntg * 16 + (lane & 15);
    int oc = ((n >> 4) & 3) * 128 + (n >> 6) * 16 + (n & 15);
    const float* wih = d ? wih1b : wih1f;
    const float* whh = d ? whh1b : whh1f;
    float v = (k < 184) ? wih[oc * 184 + k]
                        : ((k < 192) ? 0.f : whh[oc * 128 + (k - 192)]);
    wswz1[idx] = (_Float16)v;
  } else if (idx < N1 + N2) {
    int r0 = idx - N1;
    int d = r0 / 196608;
    int r = r0 - d * 196608;
    int j = r & 7, lane = (r >> 3) & 63, ntg = (r >> 9) & 31, kt = r >> 14;
    int k = kt * 32 + (lane >> 4) * 8 + j;
    int n = ntg * 16 + (lane & 15);
    int oc = ((n >> 4) & 3) * 128 + (n >> 6) * 16 + (n & 15);
    const float* wih = d ? wih2b : wih2f;
    const float* whh = d ? whh2b : whh2f;
    float v = (k < 256) ? wih[oc * 256 + k] : whh[oc * 128 + (k - 256)];
    wswz2[r0] = (_Float16)v;
  } else if (idx < N1 + N2 + NF) {
    int r = idx - (N1 + N2);
    int j = r & 7, lane = (r >> 3) & 63, ntg = (r >> 9) & 3, kt = r >> 11;
    int k = kt * 32 + (lane >> 4) * 8 + j;
    int n = ntg * 16 + (lane & 15);
    wfc[r] = (_Float16)fc1w[n * 512 + k];
  } else if (idx < N1 + N2 + NF + NB) {
    int r = idx - (N1 + N2 + NF);
    int n = r & 511, d = (r >> 9) & 1, l = r >> 10;
    int oc = ((n >> 4) & 3) * 128 + (n >> 6) * 16 + (n & 15);
    const float* bi = l ? (d ? bih2b : bih2f) : (d ? bih1b : bih1f);
    const float* bh = l ? (d ? bhh2b : bhh2f) : (d ? bhh1b : bhh1f);
    biasc[r] = bi[oc] + bh[oc];
  }
}

// ---------------------------------------------------------------------------
// x fp32 (B,10,184) -> f16 A-fragment tiles: xtile[rt][t][kt 6][q 4][m 16][8]
// element (m = row%16, k = kt*32 + q*8 + j).  Pad k>=184 zeroed.
// Wave reads 16 full 128B lines per iter (fully coalesced), writes contiguous.
// ---------------------------------------------------------------------------
__global__ void xtile_kernel(const float* __restrict__ x,
                             _Float16* __restrict__ xt) {
  int idx = blockIdx.x * 256 + threadIdx.x;  // 3,932,160 total
  int m = idx & 15;
  int q = (idx >> 4) & 3;
  int kt = (idx >> 6) % 6;
  int t = (idx / 384) % 10;
  int rt = idx / 3840;
  half8_t hv;
  if (kt == 5 && q == 3) {
#pragma unroll
    for (int j = 0; j < 8; ++j) hv[j] = (_Float16)0.f;
  } else {
    const float* src = x + ((size_t)(rt * 16 + m) * 10 + t) * 184 + kt * 32 + q * 8;
    const float4 v0 = *(const float4*)(src);
    const float4 v1 = *(const float4*)(src + 4);
    hv[0] = (_Float16)v0.x; hv[1] = (_Float16)v0.y;
    hv[2] = (_Float16)v0.z; hv[3] = (_Float16)v0.w;
    hv[4] = (_Float16)v1.x; hv[5] = (_Float16)v1.y;
    hv[6] = (_Float16)v1.z; hv[7] = (_Float16)v1.w;
  }
  *(half8_t*)(xt + (size_t)idx * 8) = hv;
}

// ---------------------------------------------------------------------------
// LSTM layer v3: 512 thr = 8 waves (one per 64-gate col strip), Mb=128 rows,
// 1 block/CU.  A-frags staged async into LDS chunks (global_load_lds, frag
// order); h in 32KB frag-order LDS; weights streamed L2->regs with a 1-kt
// prefetch chain across phases.  Schedule/t:
//   chunk0 GEMM | W2a | issue chunk1 + writeback h(t-1) + recurrent GEMM |
//   W2b | chunk1 GEMM | B_read | issue next chunk0 + cell | B_cell
// ---------------------------------------------------------------------------
#define WLOAD(kt, dst)                                                        \
  {                                                                           \
    const _Float16* _p = wd + (((size_t)(kt)*32 + (cs << 2)) * 64 + lane) * 8;\
    _Pragma("unroll") for (int _nt = 0; _nt < 4; ++_nt)                       \
        dst[_nt] = *(const half8_t*)(_p + _nt * 512);                         \
  }

#define GEMM_KT(abase, mstride, b)                                            \
  {                                                                           \
    _Pragma("unroll") for (int _mt = 0; _mt < 8; ++_mt) {                     \
      half8_t _a = *(const half8_t*)((abase) + (size_t)_mt * (mstride));      \
      _Pragma("unroll") for (int _nt = 0; _nt < 4; ++_nt)                     \
          acc[_mt][_nt] = __builtin_amdgcn_mfma_f32_16x16x32_f16(             \
              _a, (b)[_nt], acc[_mt][_nt], 0, 0, 0);                          \
    }                                                                         \
  }

template <int LAYER>
__global__ __launch_bounds__(512, 2) void lstm_kernel(
    const _Float16* __restrict__ xin, const _Float16* __restrict__ wswz,
    const float* __restrict__ biasc, _Float16* __restrict__ hout) {
  constexpr int XT = (LAYER == 1) ? 6 : 8;   // x k-tiles
  constexpr int CH = XT / 2;                 // kts per staged chunk
  constexpr int KT = XT + 4;

  __shared__ __align__(16) _Float16 Hbuf[16384];     // 32 KB, frag order
  __shared__ __align__(16) _Float16 Xbuf[CH * 4096]; // 24/32 KB

  const int tid = threadIdx.x;
  const int cs = tid >> 6;
  const int lane = tid & 63;
  const int q = lane >> 4;
  const int l15 = lane & 15;
  const int lane8 = lane * 8;
  const int dir = blockIdx.y;
  const int rt0 = blockIdx.x << 3;   // first rowtile (8 per block = 128 rows)

  const _Float16* __restrict__ wd = wswz + (size_t)dir * (KT * 16384);
  const float* __restrict__ bd = biasc + (dir << 9);

  float bias_frag[4];
#pragma unroll
  for (int nt = 0; nt < 4; ++nt) bias_frag[nt] = bd[(cs << 6) + (nt << 4) + l15];

  // async stage of chunk [c0, c0+CH) for time te into Xbuf
  auto stage = [&](int c0, int te) {
#pragma unroll
    for (int it = 0; it < (CH * 8 * 64) / 512; ++it) {
      int u = tid + it * 512;
      int mtile = u / (CH * 64);
      int rem = u - mtile * (CH * 64);
      const _Float16* g =
          xin + ((size_t)((rt0 + mtile) * 10 + te) * XT + c0) * 512 + rem * 8;
      gl_lds16(g, Xbuf + mtile * (CH * 512) + rem * 8);
    }
  };

  float c_state[8][4];
#pragma unroll
  for (int mt = 0; mt < 8; ++mt)
#pragma unroll
    for (int rg = 0; rg < 4; ++rg) c_state[mt][rg] = 0.f;

  half8_t bnx[4];
  WLOAD(0, bnx);
  stage(0, dir ? 9 : 0);
  // zero Hbuf
  {
    uint4 z = {0u, 0u, 0u, 0u};
#pragma unroll
    for (int it = 0; it < 4; ++it) *(uint4*)(Hbuf + (tid + it * 512) * 8) = z;
  }
  __syncthreads();  // chunk0(t=0) arrival + Hbuf zeros visible

  for (int t = 0; t < 10; ++t) {
    const int t_eff = dir ? (9 - t) : t;

    floatx4 acc[8][4];
#pragma unroll
    for (int mt = 0; mt < 8; ++mt)
#pragma unroll
      for (int nt = 0; nt < 4; ++nt) {
        floatx4 b4 = {bias_frag[nt], bias_frag[nt], bias_frag[nt], bias_frag[nt]};
        acc[mt][nt] = b4;
      }

    // ---- chunk0 GEMM: kts 0..CH-1 (A from Xbuf)
#pragma unroll
    for (int i = 0; i < CH; ++i) {
      half8_t bc[4];
#pragma unroll
      for (int nt = 0; nt < 4; ++nt) bc[nt] = bnx[nt];
      const int nk = (i + 1 < CH) ? (i + 1) : XT;
      WLOAD(nk, bnx);
      GEMM_KT(Xbuf + i * 512 + lane8, CH * 512, bc);
    }
    __syncthreads();  // W2a: chunk0 reads done everywhere

    stage(CH, t_eff);  // chunk1 async (overlapped by recurrent phase)

    // writeback h(t-1) while Hbuf is stable
    if (t > 0) {
      const int t_prev = dir ? (10 - t) : (t - 1);
      if (LAYER == 1) {
#pragma unroll
        for (int it = 0; it < 4; ++it) {
          int j = tid + it * 512;
          uint4 v = *(const uint4*)(Hbuf + j * 8);
          int mt = j >> 8, rem = j & 255;
          *(uint4*)(hout + ((size_t)(((rt0 + mt) * 10 + t_prev) * 8) + (dir << 2)) * 512 +
                    rem * 8) = v;
        }
      } else {
#pragma unroll
        for (int it = 0; it < 4; ++it) {
          int j = tid + it * 512;
          uint4 v = *(const uint4*)(Hbuf + j * 8);  // conflict-free (j-linear)
          int rhi = j >> 8, q2 = (j >> 6) & 3, c2 = (j >> 4) & 3, rlo = j & 15;
          *(uint4*)(hout + ((size_t)((blockIdx.x << 7) + rhi * 16 + rlo) * 10 + t_prev) * 256 +
                    (dir << 7) + (q2 * 4 + c2) * 8) = v;
        }
      }
    }

    // ---- recurrent GEMM: kts XT..XT+3 (A from Hbuf = h(t-1))
#pragma unroll
    for (int i = 0; i < 4; ++i) {
      half8_t bc[4];
#pragma unroll
      for (int nt = 0; nt < 4; ++nt) bc[nt] = bnx[nt];
      const int nk = (i < 3) ? (XT + i + 1) : CH;
      WLOAD(nk, bnx);
      GEMM_KT(Hbuf + i * 512 + lane8, 2048, bc);
    }
    __syncthreads();  // W2b: chunk1 arrived; Hbuf reads (incl. writeback) done

    // ---- chunk1 GEMM: kts CH..XT-1 (A from Xbuf)
#pragma unroll
    for (int i = 0; i < CH; ++i) {
      half8_t bc[4];
#pragma unroll
      for (int nt = 0; nt < 4; ++nt) bc[nt] = bnx[nt];
      const int nk = (i + 1 < CH) ? (CH + i + 1) : 0;  // wrap to next t chunk0
      WLOAD(nk, bnx);
      GEMM_KT(Xbuf + i * 512 + lane8, CH * 512, bc);
    }
    __syncthreads();  // B_read: all Xbuf reads done

    if (t < 9) stage(0, dir ? (8 - t) : (t + 1));  // next-t chunk0 (hidden by cell)

    // ---- LSTM cell (nt == gate); write h(t) into Hbuf (frag order)
#pragma unroll
    for (int mt = 0; mt < 8; ++mt) {
#pragma unroll
      for (int rg = 0; rg < 4; ++rg) {
        float ig = sigm_f(acc[mt][0][rg]);
        float fg = sigm_f(acc[mt][1][rg]);
        float gg = tanh_f(acc[mt][2][rg]);
        float og = sigm_f(acc[mt][3][rg]);
        float c = fg * c_state[mt][rg] + ig * gg;
        c_state[mt][rg] = c;
        float h = og * tanh_f(c);
        // frag-order offset: tile(mt, cs>>1), k_in=(cs&1)*16+l15, m=q*4+rg
        int hoff = (mt * 4 + (cs >> 1)) * 512 +
                   ((((cs & 1) * 2 + (l15 >> 3)) * 16) + (q << 2) + rg) * 8 + (l15 & 7);
        Hbuf[hoff] = (_Float16)h;
      }
    }
    __syncthreads();  // B_cell: h(t) visible; next chunk0 arrival drained
  }

  // final writeback h(t=9)
  {
    const int t_last = dir ? 0 : 9;
    if (LAYER == 1) {
#pragma unroll
      for (int it = 0; it < 4; ++it) {
        int j = tid + it * 512;
        uint4 v = *(const uint4*)(Hbuf + j * 8);
        int mt = j >> 8, rem = j & 255;
        *(uint4*)(hout + ((size_t)(((rt0 + mt) * 10 + t_last) * 8) + (dir << 2)) * 512 +
                  rem * 8) = v;
      }
    } else {
#pragma unroll
      for (int it = 0; it < 4; ++it) {
        int j = tid + it * 512;
        uint4 v = *(const uint4*)(Hbuf + j * 8);
        int rhi = j >> 8, q2 = (j >> 6) & 3, c2 = (j >> 4) & 3, rlo = j & 15;
        *(uint4*)(hout + ((size_t)((blockIdx.x << 7) + rhi * 16 + rlo) * 10 + t_last) * 256 +
                  (dir << 7) + (q2 * 4 + c2) * 8) = v;
      }
    }
  }
}

// ---------------------------------------------------------------------------
// Maxpool (groups of 5 over T) + FC 512->64 relu -> 64->1.  (unchanged)
// ---------------------------------------------------------------------------
__global__ __launch_bounds__(256) void fc_kernel(
    const _Float16* __restrict__ h2, const _Float16* __restrict__ wfc,
    const float* __restrict__ fc1b, const float* __restrict__ fc2w,
    const float* __restrict__ fc2b, float* __restrict__ out) {
  __shared__ __align__(16) _Float16 pooled[64 * 520];
  const int tid = threadIdx.x;
  const int s0 = blockIdx.x << 6;

  for (int idx = tid; idx < 64 * 128; idx += 256) {
    int s = idx >> 7;
    int part = idx & 127;
    const _Float16* base = h2 + (size_t)(s0 + s) * 10 * 256 + (part << 1);
    float m00 = -3.4e38f, m01 = -3.4e38f, m10 = -3.4e38f, m11 = -3.4e38f;
#pragma unroll
    for (int t = 0; t < 10; ++t) {
      half2_t hv = *(const half2_t*)(base + t * 256);
      float f0 = (float)hv[0], f1 = (float)hv[1];
      if (t < 5) { m00 = fmaxf(m00, f0); m10 = fmaxf(m10, f1); }
      else       { m01 = fmaxf(m01, f0); m11 = fmaxf(m11, f1); }
    }
    half4_t pv;
    pv[0] = (_Float16)m00; pv[1] = (_Float16)m01;
    pv[2] = (_Float16)m10; pv[3] = (_Float16)m11;
    *(half4_t*)(pooled + s * 520 + (part << 2)) = pv;
  }
  __syncthreads();

  const int wid = tid >> 6, lane = tid & 63, q = lane >> 4, l15 = lane & 15;
  const int m0 = wid << 4;

  const floatx4 fzero = {0.f, 0.f, 0.f, 0.f};
  floatx4 acc[4];
#pragma unroll
  for (int nt = 0; nt < 4; ++nt) acc[nt] = fzero;

#pragma unroll
  for (int kt = 0; kt < 16; ++kt) {
    half8_t a = *(const half8_t*)(pooled + (m0 + l15) * 520 + (kt << 5) + (q << 3));
#pragma unroll
    for (int nt = 0; nt < 4; ++nt) {
      half8_t b = *(const half8_t*)(wfc + ((((size_t)kt << 2) + nt) * 64 + lane) * 8);
      acc[nt] = __builtin_amdgcn_mfma_f32_16x16x32_f16(a, b, acc[nt], 0, 0, 0);
    }
  }

  float b1[4], w2[4];
#pragma unroll
  for (int nt = 0; nt < 4; ++nt) {
    b1[nt] = fc1b[(nt << 4) + l15];
    w2[nt] = fc2w[(nt << 4) + l15];
  }
  const float c2b = fc2b[0];

#pragma unroll
  for (int rg = 0; rg < 4; ++rg) {
    float v = 0.f;
#pragma unroll
    for (int nt = 0; nt < 4; ++nt)
      v += fmaxf(acc[nt][rg] + b1[nt], 0.f) * w2[nt];
    v += __shfl_xor(v, 1, 64);
    v += __shfl_xor(v, 2, 64);
    v += __shfl_xor(v, 4, 64);
    v += __shfl_xor(v, 8, 64);
    if (l15 == 0) out[s0 + m0 + (q << 2) + rg] = v + c2b;
  }
}

// ---------------------------------------------------------------------------
extern "C" void kernel_launch(void* const* d_in, const int* in_sizes, int n_in,
                              void* d_out, int out_size, void* d_ws, size_t ws_size,
                              hipStream_t stream) {
  const float* x     = (const float*)d_in[0];
  const float* wih1f = (const float*)d_in[1];
  const float* whh1f = (const float*)d_in[2];
  const float* bih1f = (const float*)d_in[3];
  const float* bhh1f = (const float*)d_in[4];
  const float* wih1b = (const float*)d_in[5];
  const float* whh1b = (const float*)d_in[6];
  const float* bih1b = (const float*)d_in[7];
  const float* bhh1b = (const float*)d_in[8];
  const float* wih2f = (const float*)d_in[9];
  const float* whh2f = (const float*)d_in[10];
  const float* bih2f = (const float*)d_in[11];
  const float* bhh2f = (const float*)d_in[12];
  const float* wih2b = (const float*)d_in[13];
  const float* whh2b = (const float*)d_in[14];
  const float* bih2b = (const float*)d_in[15];
  const float* bhh2b = (const float*)d_in[16];
  const float* fc1w  = (const float*)d_in[17];
  const float* fc1b  = (const float*)d_in[18];
  const float* fc2w  = (const float*)d_in[19];
  const float* fc2b  = (const float*)d_in[20];
  float* out = (float*)d_out;

  // workspace (169,287,680 B):
  //   region A: xtile (62.9 MB) during xtile+lstm1, then h2out (83.9 MB)
  //   region B: h1out tiled (83.9 MB)
  if (ws_size < (size_t)169287680) return;
  _Float16* regionA = (_Float16*)d_ws;
  _Float16* xtile = regionA;                    // [1024][10][6][512] f16
  _Float16* h2out = regionA;                    // [16384][10][256] f16 (linear)
  _Float16* h1out = regionA + (size_t)41943040; // [1024][10][8][512] f16 (tiled)
  _Float16* wswz1 = h1out + (size_t)41943040;
  _Float16* wswz2 = wswz1 + 327680;
  _Float16* wfc   = wswz2 + 393216;
  float* biasc    = (float*)(wfc + 32768);

  prep_kernel<<<2952, 256, 0, stream>>>(
      wih1f, whh1f, bih1f, bhh1f, wih1b, whh1b, bih1b, bhh1b,
      wih2f, whh2f, bih2f, bhh2f, wih2b, whh2b, bih2b, bhh2b, fc1w,
      wswz1, wswz2, wfc, biasc);
  xtile_kernel<<<15360, 256, 0, stream>>>(x, xtile);
  lstm_kernel<1><<<dim3(128, 2), 512, 0, stream>>>(xtile, wswz1, biasc, h1out);
  lstm_kernel<2><<<dim3(128, 2), 512, 0, stream>>>(h1out, wswz2, biasc + 1024, h2out);
  fc_kernel<<<256, 256, 0, stream>>>(h2out, wfc, fc1b, fc2w, fc2b, out);
}